// Round 20
// baseline (160.135 us; speedup 1.0000x reference)
//
#include <hip/hip_runtime.h>
#include <stdint.h>
#include <math.h>

// Validated semantics (r17-r19 green): printed reference, fp32 in/out.
//   sig[b,h,j] = sigmoid(delta[j,b,h]/sqrt(32));  p[b,j] = 0.125*sum_h sig
//   delta = sum_e D*(U+V), mu folded: = sum(s-o)w - ((sum s-sum o)/256)*sum w
//   U[h,e,j] = sum_{d in h} QwT[d,j]*Wk[d,e],  QwT = Qp[256+j]@Wq^T
//   V[b,h,e] = sum_{d in h} (Pq[b,d]+bq[d])*Wk[d,e],  Pq = pe[b]@Wq^T
//   new_state[b,e,l<256]=state; l>=256: p*s_l+(1-p)*o_{l-256}
//   atten[b,l,s]: l<256 -> 1 at s=l; else p at s=l, 1-p at s=l+256.
// r20: sigmoids written raw per (b,h) (no zero-init, no atomics); k_out sums
// 8 h-values inline (L2-resident 256 KB). float4 ns stores (2 rows/block).

// d_ws layout (floats)
#define WS_QWT  0        // [256 d][256 j]
#define WS_PQ   65536    // [32 b][256 d]
#define WS_U    73728    // [8 h][256 e][256 j]
#define WS_V    598016   // [32 b][8 h][256 e]
#define WS_SIG  663552   // [32 b][8 h][256 j]
// end 729088 floats = 2.85 MB (ws_size >= 3.3 MB proven)

// ---------------------------------------------------------------------------
// K1 prologue: QwT (256 blocks), Pq with in-block pe (32).  288 blocks.
__global__ void k_pro(const float* __restrict__ Qp, const float* __restrict__ Wq,
                      float* __restrict__ ws) {
  __shared__ float row[256];
  int bid = blockIdx.x, t = threadIdx.x;
  if (bid < 256) {                      // QwT[d][j] = sum_e Qp[256+j][e]*Wq[d][e]
    int d = bid;
    row[t] = Wq[(size_t)d * 256 + t];
    __syncthreads();
    const float* qrow = Qp + (size_t)(256 + t) * 256;   // t = j
    float acc = 0.f;
    for (int e = 0; e < 256; ++e) acc += qrow[e] * row[e];
    ws[WS_QWT + d * 256 + t] = acc;
  } else {                              // Pq[b][d] = sum_e pe[b][e]*Wq[d][e]
    int b = bid - 256;
    {                                   // pe[b][e] for e = t
      int k2 = t & ~1;                  // arange value 2k
      float div = expf((float)k2 * (-9.210340371976184f / 256.f));
      float a = (float)b * div;
      row[t] = (t & 1) ? cosf(a) : sinf(a);
    }
    __syncthreads();
    const float* wrow = Wq + (size_t)t * 256;           // t = d
    float acc = 0.f;
    for (int e = 0; e < 256; ++e) acc += row[e] * wrow[e];
    ws[WS_PQ + b * 256 + t] = acc;
  }
}

// ---------------------------------------------------------------------------
// K2: U[h][e][j] and V[b][h][e].  2304 blocks x 256.
__global__ void k_uv(const float* __restrict__ Wk, const float* __restrict__ bq,
                     float* __restrict__ ws) {
  int bid = blockIdx.x, t = threadIdx.x;
  if (bid < 2048) {
    int h = bid >> 8, e = bid & 255;
    float acc = 0.f;
#pragma unroll 8
    for (int dd = 0; dd < 32; ++dd) {
      int d = h * 32 + dd;
      acc += ws[WS_QWT + d * 256 + t] * Wk[(size_t)d * 256 + e];
    }
    ws[WS_U + ((h << 8) + e) * 256 + t] = acc;
  } else {
    int idx = bid - 2048, b = idx >> 3, h = idx & 7;
    float acc = 0.f;
#pragma unroll 8
    for (int dd = 0; dd < 32; ++dd) {
      int d = h * 32 + dd;
      acc += (ws[WS_PQ + b * 256 + d] + bq[d]) * Wk[(size_t)d * 256 + t];
    }
    ws[WS_V + ((b << 3) + h) * 256 + t] = acc;
  }
}

// ---------------------------------------------------------------------------
// K3: delta (mu inline, single state/obs pass) -> sigmoid raw write.
// 256 blocks = (b,h) x 256 threads = j.  No atomics, no zero-init.
__global__ void k_delta(const float* __restrict__ state, const float* __restrict__ obs,
                        float* __restrict__ ws) {
  int b = blockIdx.x >> 3, h = blockIdx.x & 7;
  int j = threadIdx.x;
  __shared__ float vsh[256];
  vsh[j] = ws[WS_V + ((b << 3) + h) * 256 + j];
  __syncthreads();
  const float* Uh = ws + WS_U + (h << 16);
  const float* sp = state + (size_t)b * 131072 + 256 + j;
  const float* op = obs + (size_t)b * 65536 + j;
  float a_sw = 0.f, a_w = 0.f, a_s = 0.f, a_o = 0.f;
#pragma unroll 4
  for (int e = 0; e < 256; ++e) {
    float s = sp[(size_t)e * 512];
    float o = op[(size_t)e * 256];
    float w = Uh[(e << 8) + j] + vsh[e];
    a_sw += (s - o) * w;
    a_w  += w;
    a_s  += s;
    a_o  += o;
  }
  float delta = a_sw - (a_s - a_o) * (1.f / 256.f) * a_w;
  float ph = 1.f / (1.f + __expf(-delta * 0.17677669529663687f)); // /sqrt(32)
  ws[WS_SIG + ((b << 3) + h) * 256 + j] = ph;
}

// ---------------------------------------------------------------------------
// inline p from the 8 per-head sigmoids (L2-resident 256 KB array)
__device__ __forceinline__ float get_p(const float* __restrict__ ws, int b, int j) {
  const float* s = ws + WS_SIG + (b << 11) + j;
  float acc = 0.f;
#pragma unroll
  for (int h = 0; h < 8; ++h) acc += s[h << 8];
  return acc * 0.125f;
}

// ---------------------------------------------------------------------------
// K4 fused output.  16384 blocks: [0,4096) ns (2 rows each, float4); rest atten.
__global__ void k_out(const float* __restrict__ state, const float* __restrict__ obs,
                      const float* __restrict__ ws, float* __restrict__ out) {
  int bid = blockIdx.x, t = threadIdx.x;
  if (bid < 4096) {                     // two new_state rows (same b)
    int row = bid * 2 + (t >> 7);       // (b,e) row index
    int c = t & 127;                    // float4 index in row (l = 4c)
    int b = bid >> 7;
    const float4* s4 = (const float4*)(state + (size_t)row * 512);
    float4* o4 = (float4*)(out + (size_t)row * 512);
    float4 sv = s4[c];
    if (c < 64) {
      o4[c] = sv;                       // l < 256: identity
    } else {
      int j0 = 4 * c - 256;
      float4 ov = ((const float4*)(obs + (size_t)row * 256))[c - 64];
      float p0 = get_p(ws, b, j0);
      float p1 = get_p(ws, b, j0 + 1);
      float p2 = get_p(ws, b, j0 + 2);
      float p3 = get_p(ws, b, j0 + 3);
      float4 r;
      r.x = p0 * sv.x + (1.f - p0) * ov.x;
      r.y = p1 * sv.y + (1.f - p1) * ov.y;
      r.z = p2 * sv.z + (1.f - p2) * ov.z;
      r.w = p3 * sv.w + (1.f - p3) * ov.w;
      o4[c] = r;
    }
  } else {                              // atten, one float4 per thread
    int g4 = (bid - 4096) * 256 + t;    // 0..3145727
    int r = g4 / 192, c = g4 - r * 192; // r = b*512 + l
    int b = r >> 9, l = r & 511;
    int s0 = c << 2;
    float v[4] = {0.f, 0.f, 0.f, 0.f};
    if (l < 256) {
      if (l >= s0 && l < s0 + 4) v[l - s0] = 1.0f;
    } else {
      bool in1 = (l >= s0 && l < s0 + 4);
      int s2 = l + 256;
      bool in2 = (s2 >= s0 && s2 < s0 + 4);
      if (in1 || in2) {
        float p = get_p(ws, b, l - 256);
        if (in1) v[l - s0] = p;
        if (in2) v[s2 - s0] = 1.0f - p;
      }
    }
    float4 val; val.x = v[0]; val.y = v[1]; val.z = v[2]; val.w = v[3];
    ((float4*)(out + 4194304))[g4] = val;
  }
}

extern "C" void kernel_launch(void* const* d_in, const int* in_sizes, int n_in,
                              void* d_out, int out_size, void* d_ws, size_t ws_size,
                              hipStream_t stream) {
  const float *state = nullptr, *obs = nullptr, *Qp = nullptr;
  const float *Wq = nullptr, *Wk = nullptr, *bq = nullptr, *bk = nullptr;
  for (int i = 0; i < n_in; ++i) {
    int s = in_sizes[i];
    const float* p = (const float*)d_in[i];
    if      (s == 4194304) state = p;
    else if (s == 2097152) obs = p;
    else if (s == 131072)  Qp = p;
    else if (s == 65536)   { if (!Wq) Wq = p; else Wk = p; }
    else if (s == 256)     { if (!bq) bq = p; else bk = p; }
  }
  (void)bk;                             // cancels in the 2-way softmax
  float* out = (float*)d_out;
  float* ws  = (float*)d_ws;

  k_pro  <<<288,   256, 0, stream>>>(Qp, Wq, ws);
  k_uv   <<<2304,  256, 0, stream>>>(Wk, bq, ws);
  k_delta<<<256,   256, 0, stream>>>(state, obs, ws);
  k_out  <<<16384, 256, 0, stream>>>(state, obs, ws, out);
}